// Round 6
// baseline (186.790 us; speedup 1.0000x reference)
//
#include <hip/hip_runtime.h>

#define SEQ_N 1024   // sequence length (n == m == 1024)
#define BATCH 64     // batch size
#define RPL   16     // rows per lane (64 lanes * 16 = 1024)
#define PAD_F 64     // LDS front pad (floats) -> unclamped yp[s] reads stay in-bounds
#define PAD_B 128    // LDS back pad

// Wave-wide shift-up-by-1 in ONE instruction: DPP wave_shr:1 (ctrl 0x138).
// bound_ctrl=false -> lane 0 takes `fill` (INF) = top-row boundary for free.
__device__ __forceinline__ float wave_shr1(float v, float fill) {
    return __int_as_float(__builtin_amdgcn_update_dpp(
        __float_as_int(fill), __float_as_int(v), 0x138, 0xF, 0xF, false));
}

// Exact-instruction cell ops (no canonicalization, abs as free src modifier).
// Register-only single-instruction asm: deps carried by operands, safe to
// schedule; HW reads sources before writing dest so no early-clobber needed.
__device__ __forceinline__ float add_abs(float a, float d) {   // a + |d|
    float r;
    asm("v_add_f32 %0, %1, |%2|" : "=v"(r) : "v"(a), "v"(d));
    return r;
}
__device__ __forceinline__ float min3(float a, float b, float c) {
    float r;
    asm("v_min3_f32 %0, %1, %2, %3" : "=v"(r) : "v"(a), "v"(b), "v"(c));
    return r;
}

// One WAVE per batch element; lane l owns rows [l*16, l*16+16) in registers.
// Lane-skewed wavefront: at step s, lane l computes column j = s - l.
// Cell: D = d + min3(diag + d, left, up):
//   off-chain: diff[r] = xr[r] - yj            (v_sub)
//              tt[r]   = old col[r-1] + |diff| (v_add abs-mod)
//   chain:     v = min3(tt[r], col[r], v); v = v + |diff|   (v_min3, v_add)
// = exactly 4 VALU/cell.
__global__ __launch_bounds__(64) void dtw_wave_kernel(const float* __restrict__ x,
                                                      const float* __restrict__ y,
                                                      float* __restrict__ dists) {
    __shared__ float sy_raw[PAD_F + SEQ_N + PAD_B];
    float* const sy = sy_raw + PAD_F;

    const int b = blockIdx.x;
    const int l = threadIdx.x;   // 0..63
    const float INF = 3.0e37f;

    sy_raw[l] = 0.0f;
    sy_raw[PAD_F + SEQ_N + l] = 0.0f;
    sy_raw[PAD_F + SEQ_N + 64 + l] = 0.0f;

    const float4* y4 = (const float4*)(y + b * SEQ_N);
    float4* sy4 = (float4*)sy;
    #pragma unroll
    for (int i = 0; i < SEQ_N / 4 / 64; ++i)
        sy4[l + i * 64] = y4[l + i * 64];

    float xr[RPL];
    const float4* x4 = (const float4*)(x + b * SEQ_N + l * RPL);
    #pragma unroll
    for (int i = 0; i < RPL / 4; ++i) {
        float4 v4 = x4[i];
        xr[i*4+0] = v4.x; xr[i*4+1] = v4.y; xr[i*4+2] = v4.z; xr[i*4+3] = v4.w;
    }
    __syncthreads();

    float col[RPL];
    #pragma unroll
    for (int r = 0; r < RPL; ++r) col[r] = INF;
    float diag_top = INF;   // neighbor bottom from 2 steps ago
    float bottom   = INF;   // this lane's col[15]

    const float* const yp = sy - l;   // yp[s] == y[s - l] (pads keep it in-bounds)

#define DTW_STEP(YJ, UP, DG)                                               \
    {                                                                      \
        const float up_ = (UP);                                            \
        const float yj_ = (YJ);                                            \
        float diff[RPL], tt[RPL];                                          \
        _Pragma("unroll")                                                  \
        for (int r = 0; r < RPL; ++r) diff[r] = xr[r] - yj_;               \
        tt[0] = add_abs((DG), diff[0]);                                    \
        _Pragma("unroll")                                                  \
        for (int r = 1; r < RPL; ++r) tt[r] = add_abs(col[r-1], diff[r]);  \
        float v = up_;                                                     \
        _Pragma("unroll")                                                  \
        for (int r = 0; r < RPL; ++r) {                                    \
            v = add_abs(min3(tt[r], col[r], v), diff[r]);                  \
            col[r] = v;                                                    \
        }                                                                  \
        diag_top = up_;                                                    \
        bottom   = v;                                                      \
    }

    // ---- phase A: s in [0, 64), lanes l <= s active ----
    float ycur = yp[0];
    for (int s = 0; s < 64; ++s) {
        const float up_dpp = wave_shr1(bottom, INF);
        const float ynext = yp[s + 1];
        if (s >= l) {
            const float up = (l == 0) ? ((s == 0) ? 0.0f : INF) : up_dpp;
            const float dg = (l == 0) ? INF : diag_top;
            DTW_STEP(ycur, up, dg);
        }
        ycur = ynext;
    }

    // ---- phase B: s in [64, 1024), ALL lanes active, zero masks ----
    // lane 0: up == INF via DPP fill; diag_top == INF by induction.
    float y0 = ycur;       // y for step s
    float y1 = yp[65];     // y for step s+1
    for (int s = 64; s < SEQ_N; s += 2) {
        const float up0 = wave_shr1(bottom, INF);
        const float y2 = yp[s + 2];
        DTW_STEP(y0, up0, diag_top);
        const float up1 = wave_shr1(bottom, INF);
        const float y3 = yp[s + 3];
        DTW_STEP(y1, up1, diag_top);
        y0 = y2; y1 = y3;
    }

    // ---- phase C: s in [1024, 1087), lanes l >= s-1023 active ----
    for (int s = SEQ_N; s < SEQ_N + 63; ++s) {
        const float up = wave_shr1(bottom, INF);
        const float yn = yp[s + 2];
        if (s - l < SEQ_N) {
            DTW_STEP(y0, up, diag_top);
        }
        y0 = y1; y1 = yn;
    }
#undef DTW_STEP

    if (l == 63) dists[b] = col[RPL - 1] * (1.0f / (2.0f * (float)SEQ_N));
}

// Mean over the 64 per-batch distances -> single float output.
__global__ void dtw_reduce_kernel(const float* __restrict__ dists,
                                  float* __restrict__ out) {
    float v = dists[threadIdx.x] * (1.0f / (float)BATCH);
    #pragma unroll
    for (int o = 32; o > 0; o >>= 1) v += __shfl_down(v, o);
    if (threadIdx.x == 0) out[0] = v;
}

extern "C" void kernel_launch(void* const* d_in, const int* in_sizes, int n_in,
                              void* d_out, int out_size, void* d_ws, size_t ws_size,
                              hipStream_t stream) {
    const float* x = (const float*)d_in[0];
    const float* y = (const float*)d_in[1];
    float* out = (float*)d_out;
    float* dists = (float*)d_ws;  // 64 floats of scratch

    dtw_wave_kernel<<<BATCH, 64, 0, stream>>>(x, y, dists);
    dtw_reduce_kernel<<<1, BATCH, 0, stream>>>(dists, out);
}

// Round 8
// 88.697 us; speedup vs baseline: 2.1059x; 2.1059x over previous
//
#include <hip/hip_runtime.h>

#define SEQ_N 1024
#define BATCH 64
#define NW    4            // waves per block (per batch element)
#define RPL   4            // rows per lane: 4 waves * 64 lanes * 4 = 1024 rows
#define KSL   16           // epoch length == inter-wave slack - 1
#define DELTA (64 + KSL)   // column delay between consecutive waves (80)
#define RINGN 80           // 64-slot ring + 16 mirror slots (wrap-free reads)
#define PAD_F 304          // front pad: max off = 3*80+63 = 303
#define PAD_B 352          // back pad: last y prefetch index = 1359

// Wave-wide shift-up-by-1 in one instruction (DPP wave_shr:1, ctrl 0x138).
// bound_ctrl=false -> lane 0 takes `fill` (INF) = top-row boundary for free.
__device__ __forceinline__ float wave_shr1(float v, float fill) {
    return __int_as_float(__builtin_amdgcn_update_dpp(
        __float_as_int(fill), __float_as_int(v), 0x138, 0xF, 0xF, false));
}

// 4 waves cooperate on one DTW matrix. Wave w owns rows [w*256, w*256+256),
// lane l of wave w owns rows w*256 + l*4 .. +4. Lane (w,l) at global step s
// computes column j = s - w*DELTA - l.
//
// Cross-lane dep: DPP wave_shr1 (in-wave). Cross-wave dep: wave w-1 lane63's
// bottom row flows to wave w lane0 via an LDS ring (slot = step & 63; slack
// is 17 steps). One barrier per 16-step epoch: value produced at step p is
// written at the end of p's epoch, consumed at p+17 (>= 1 barrier later),
// slot overwritten at p+64 (>= 2 barriers after last read).
//
// Corner seed (the v6 bug): D[0,0] must see up=0 (so D[0,0]=d). Applied only
// at (first epoch, k2==0, tid==0); diag_top is then restored to INF so cell
// (0,1) doesn't inherit the 0 through the diag path.
__global__ __launch_bounds__(256, 1) void dtw_kernel(const float* __restrict__ x,
                                                     const float* __restrict__ y,
                                                     float* __restrict__ dists) {
    __shared__ float sy_raw[PAD_F + SEQ_N + PAD_B];
    __shared__ float ring[NW - 1][RINGN];

    const int b   = blockIdx.x;
    const int tid = threadIdx.x;
    const int w   = tid >> 6;        // wave id 0..3
    const int l   = tid & 63;        // lane id
    const float INF = 3.0e37f;
    const int  off = w * DELTA + l;  // column delay of this lane
    const bool is_ring_l0 = (l == 0) && (w > 0);
    const bool is_tid0 = (tid == 0);

    // zero pads
    for (int i = tid; i < PAD_F; i += 256) sy_raw[i] = 0.0f;
    for (int i = tid; i < PAD_B; i += 256) sy_raw[PAD_F + SEQ_N + i] = 0.0f;
    // stage y (one float4 per thread)
    ((float4*)(sy_raw + PAD_F))[tid] = ((const float4*)(y + b * SEQ_N))[tid];
    // this lane's 4 x-rows (one float4)
    const float4 xv = *((const float4*)(x + b * SEQ_N + w * 256 + l * RPL));
    const float xr0 = xv.x, xr1 = xv.y, xr2 = xv.z, xr3 = xv.w;
    __syncthreads();

    const float* const yp = sy_raw + PAD_F - off;   // yp[s] == y[s - off]

    float c0 = INF, c1 = INF, c2 = INF, c3 = INF;   // col[0..3]
    float diag_top = INF, bottom = INF;
    float yA[KSL], yB[KSL], rb[KSL], bt[KSL];

    // prologue: y values for epoch 0
    #pragma unroll
    for (int k = 0; k < KSL; ++k) yA[k] = yp[k];

// One 16-step epoch. YU = y values for this epoch, YF = buffer filled with
// next epoch's y. Ring values for the whole epoch are read right after the
// barrier; bottoms are collected in bt[] and written at epoch end.
#define EPOCH(MASKED, FIRST, S0, YU, YF)                                     \
  {                                                                          \
    __syncthreads();                                                         \
    if (w > 0) {                                                             \
      int rbase = ((S0) & 63) + 47; if (rbase >= 64) rbase -= 64;            \
      const float* rp = ring[w - 1] + rbase;                                 \
      _Pragma("unroll")                                                      \
      for (int k2 = 0; k2 < KSL; ++k2) rb[k2] = rp[k2];                      \
    } else {                                                                 \
      _Pragma("unroll")                                                      \
      for (int k2 = 0; k2 < KSL; ++k2) rb[k2] = INF;                         \
    }                                                                        \
    _Pragma("unroll")                                                        \
    for (int k2 = 0; k2 < KSL; ++k2) YF[k2] = yp[(S0) + KSL + k2];           \
    _Pragma("unroll")                                                        \
    for (int k2 = 0; k2 < KSL; ++k2) {                                       \
      const float up_dpp = wave_shr1(bottom, INF);                           \
      float upv = is_ring_l0 ? rb[k2] : up_dpp;                              \
      if ((FIRST) && k2 == 0 && is_tid0) upv = 0.0f;  /* seed D[0,0]=d */    \
      const float yj = YU[k2];                                               \
      bool act = true;                                                       \
      if (MASKED) act = ((unsigned)((S0) + k2 - off) < (unsigned)SEQ_N);     \
      if (act) {                                                             \
        const float d0 = xr0 - yj, d1 = xr1 - yj,                            \
                    d2 = xr2 - yj, d3 = xr3 - yj;                            \
        const float t0 = diag_top + fabsf(d0);                               \
        const float t1 = c0 + fabsf(d1);                                     \
        const float t2 = c1 + fabsf(d2);                                     \
        const float t3 = c2 + fabsf(d3);                                     \
        float v = upv;                                                       \
        v = fminf(fminf(t0, c0), v) + fabsf(d0); c0 = v;                     \
        v = fminf(fminf(t1, c1), v) + fabsf(d1); c1 = v;                     \
        v = fminf(fminf(t2, c2), v) + fabsf(d2); c2 = v;                     \
        v = fminf(fminf(t3, c3), v) + fabsf(d3); c3 = v;                     \
        diag_top = upv; bottom = v;                                          \
      }                                                                      \
      if ((FIRST) && k2 == 0 && is_tid0) diag_top = INF; /* un-contaminate */\
      bt[k2] = bottom;                                                       \
    }                                                                        \
    if (w < NW - 1 && l == 63) {                                             \
      const int mm = (S0) & 63;                                              \
      float* wp = ring[w] + mm;                                              \
      _Pragma("unroll")                                                      \
      for (int k2 = 0; k2 < KSL; ++k2) wp[k2] = bt[k2];                      \
      if (mm == 0) {                                                         \
        _Pragma("unroll")                                                    \
        for (int k2 = 0; k2 < KSL; ++k2) ring[w][64 + k2] = bt[k2];          \
      }                                                                      \
    }                                                                        \
  }

    // epoch 0 (with corner seed) + epoch 1
    EPOCH(true, true, 0, yA, yB);
    EPOCH(true, false, 16, yB, yA);
    int s0 = 32;
    // epochs 2..19: ramp-up (some lanes inactive)
    for (int it = 1; it < 10; ++it) {
        EPOCH(true, false, s0, yA, yB);
        EPOCH(true, false, s0 + 16, yB, yA);
        s0 += 32;
    }
    // epochs 20..63: steady, all 1024 lanes interior (steps 320..1023)
    for (int it = 0; it < 22; ++it) {
        EPOCH(false, false, s0, yA, yB);
        EPOCH(false, false, s0 + 16, yB, yA);
        s0 += 32;
    }
    // epochs 64..83: ramp-down (steps 1024..1343; last active step is 1326)
    for (int it = 0; it < 10; ++it) {
        EPOCH(true, false, s0, yA, yB);
        EPOCH(true, false, s0 + 16, yB, yA);
        s0 += 32;
    }
#undef EPOCH

    // D[1023,1023] lives in wave 3 lane 63's c3
    if (tid == 255) dists[b] = c3 * (1.0f / (2.0f * (float)SEQ_N));
}

// Mean over the 64 per-batch distances -> single float output.
__global__ void dtw_reduce_kernel(const float* __restrict__ dists,
                                  float* __restrict__ out) {
    float v = dists[threadIdx.x] * (1.0f / (float)BATCH);
    #pragma unroll
    for (int o = 32; o > 0; o >>= 1) v += __shfl_down(v, o);
    if (threadIdx.x == 0) out[0] = v;
}

extern "C" void kernel_launch(void* const* d_in, const int* in_sizes, int n_in,
                              void* d_out, int out_size, void* d_ws, size_t ws_size,
                              hipStream_t stream) {
    const float* x = (const float*)d_in[0];
    const float* y = (const float*)d_in[1];
    float* out = (float*)d_out;
    float* dists = (float*)d_ws;  // 64 floats of scratch

    dtw_kernel<<<BATCH, 256, 0, stream>>>(x, y, dists);
    dtw_reduce_kernel<<<1, BATCH, 0, stream>>>(dists, out);
}